// Round 21
// baseline (394.447 us; speedup 1.0000x reference)
//
#include <hip/hip_runtime.h>
#include <math.h>

#define NB 32

typedef _Float16 half_t;
typedef _Float16 half8 __attribute__((ext_vector_type(8)));
typedef float f32x4 __attribute__((ext_vector_type(4)));

// fragment blob indices (each fragment = 512 half = 1 KB, lane-major: lane*8 halfs)
// B-frag: lane l holds B[k = ks*32 + (l>>4)*8 + j][n = ct*16 + (l&15)], j=0..7
// hi blob at frag f, lo blob at frag FR_TOTAL + f.
#define FR_G1  0      // ks(2)*16 + ct(16)                  -> 32 frags
#define FR_G2  32     // 32 + ks(8)*16 + ct(16)             -> 128
#define FR_SP  160    // 160 + layer*56 + ks(8)*7 + ct(7)   -> 224 (cols >=97 zero)
#define FR_AFF 384    // 384 + ks(8)                        -> 8 (cols >=4 zero)
#define FR_TOTAL 392  // hi+lo = 784 KB in d_ws

__device__ __forceinline__ void split16(float x, half_t& h, half_t& l) {
    h = (half_t)x;
    l = (half_t)(x - (float)h);
}

__global__ __launch_bounds__(64) void prep_kernel(
    const float* __restrict__ w1, const float* __restrict__ w2,
    const float* __restrict__ sw, const float* __restrict__ aw,
    half_t* __restrict__ frags)
{
    const int f = blockIdx.x;
    const int l = threadIdx.x;
    const int kl = (l >> 4) * 8;
    const int nl = l & 15;
    half8 vh, vl;
    #pragma unroll
    for (int j = 0; j < 8; ++j) {
        float w = 0.f;
        if (f < FR_G2) {
            int ks = f >> 4, ct = f & 15;
            w = w1[(ks * 32 + kl + j) * 256 + ct * 16 + nl];
        } else if (f < FR_SP) {
            int g = f - FR_G2;
            int ks = g >> 4, ct = g & 15;
            w = w2[(ks * 32 + kl + j) * 256 + ct * 16 + nl];
        } else if (f < FR_AFF) {
            int g = f - FR_SP;
            int layer = g / 56, r = g - layer * 56;
            int ks = r / 7, ct = r - ks * 7;
            int n = ct * 16 + nl;
            if (n < 97) w = sw[(size_t)layer * 24832 + (size_t)(ks * 32 + kl + j) * 97 + n];
        } else {
            int ks = f - FR_AFF;
            if (nl < 4) w = aw[(ks * 32 + kl + j) * 4 + nl];
        }
        half_t h, lo;
        split16(w, h, lo);
        vh[j] = h; vl[j] = lo;
    }
    *reinterpret_cast<half8*>(frags + (size_t)f * 512 + l * 8) = vh;
    *reinterpret_cast<half8*>(frags + (size_t)(FR_TOTAL + f) * 512 + l * 8) = vl;
}

__device__ __forceinline__ float softplus_f(float v) {
    return v > 0.f ? v + log1pf(__expf(-v)) : log1pf(__expf(v));
}

// Cooperative RQS on a LANE PAIR: lane (t&1)==l2 owns bins [l2*16, l2*16+16).
// p -> row's 97 params in LDS (read-only). Returns y (both lanes of the pair).
__device__ __forceinline__ float rqs_coop2(float x, const float* __restrict__ p, int lane) {
    const float RMIN = -3.0f;
    const float total = 6.0f - 32.0f * 1e-5f;
    const float OFF = 0.54130903f;                // log(exp(1-1e-5)-1)
    const int l2 = lane & 1;
    const int b0 = l2 * 16;

    // pass 1: pair max
    float mw = -INFINITY, mh = -INFINITY;
    #pragma unroll
    for (int i = 0; i < 16; ++i) {
        mw = fmaxf(mw, p[b0 + i]);
        mh = fmaxf(mh, p[NB + b0 + i]);
    }
    mw = fmaxf(mw, __shfl_xor(mw, 1));
    mh = fmaxf(mh, __shfl_xor(mh, 1));

    // pass 2: pair softmax denominators
    float swd = 0.f, shd = 0.f;
    #pragma unroll
    for (int i = 0; i < 16; ++i) {
        swd += __expf(p[b0 + i] - mw);
        shd += __expf(p[NB + b0 + i] - mh);
    }
    float swdo = __shfl_xor(swd, 1);
    float shdo = __shfl_xor(shd, 1);
    float sw_scale = total / (swd + swdo);
    float sh_scale = total / (shd + shdo);
    float prew = l2 ? (swdo * sw_scale + 16.f * 1e-5f) : 0.f;
    float preh = l2 ? (shdo * sh_scale + 16.f * 1e-5f) : 0.f;

    // pass 3: recompute exps, running cumsum, predicated capture of containing bin
    float cumw = 0.f, cumh = 0.f;
    float cw_c = 0.f, ch_c = 0.f, wk_c = 1.f, hk_c = 1.f;
    int idx_c = 0, cap = 0;
    #pragma unroll
    for (int i = 0; i < 16; ++i) {
        float wi = __expf(p[b0 + i] - mw) * sw_scale + 1e-5f;
        float hi = __expf(p[NB + b0 + i] - mh) * sh_scale + 1e-5f;
        float lw = prew + cumw;
        if (x >= RMIN + lw) {
            cw_c = lw; ch_c = preh + cumh; wk_c = wi; hk_c = hi;
            idx_c = b0 + i; cap = 1;
        }
        cumw += wi; cumh += hi;
    }

    // pair combine: lane1's capture wins when present
    const int hi_l = lane | 1, lo_l = lane & ~1;
    int   cap1 = __shfl(cap,  hi_l);
    float cw1 = __shfl(cw_c, hi_l), cw0 = __shfl(cw_c, lo_l);
    float ch1 = __shfl(ch_c, hi_l), ch0 = __shfl(ch_c, lo_l);
    float wk1 = __shfl(wk_c, hi_l), wk0 = __shfl(wk_c, lo_l);
    float hk1 = __shfl(hk_c, hi_l), hk0 = __shfl(hk_c, lo_l);
    int   ix1 = __shfl(idx_c, hi_l), ix0 = __shfl(idx_c, lo_l);
    float cw = cap1 ? cw1 : cw0;
    float ch = cap1 ? ch1 : ch0;
    float wk = cap1 ? wk1 : wk0;
    float hk = cap1 ? hk1 : hk0;
    int   idx = cap1 ? ix1 : ix0;

    float dk  = softplus_f(p[2 * NB + idx] + OFF) + 1e-5f;
    float dk1 = softplus_f(p[2 * NB + idx + 1] + OFF) + 1e-5f;

    float xk = RMIN + cw, yk = RMIN + ch;
    float z = (x - xk) / wk;
    z = fminf(fmaxf(z, 0.f), 1.f);
    float s = hk / wk;
    float z1 = z * (1.f - z);
    float num = hk * (s * z * z + dk * z1);
    float den = s + (dk1 + dk - 2.f * s) * z1;
    float y = yk + num / den;
    return (x < -3.0f || x > 3.0f) ? x : y;
}

#define LT 264    // lat16 row stride in halfs (528B)
#define PST 105   // pbuf row stride in floats (odd -> bank-spread reads)

// 32 rows/block, 512 threads (8 waves), LDS ~61 KB (free band per r17/r19 data).
__global__ __launch_bounds__(512, 4) void condflow_kernel(
    const float* __restrict__ cond, const float* __restrict__ t_in,
    const float* __restrict__ b1, const float* __restrict__ b2,
    const float* __restrict__ sb, const float* __restrict__ ab,
    const half_t* __restrict__ frags,
    float* __restrict__ out)
{
    __shared__ half_t lat16h[32 * LT];    // 16896 B
    __shared__ half_t lat16l[32 * LT];    // 16896 B
    __shared__ float pbuf[2][32][PST];    // 26880 B (double-buffered: layer L -> buf L&1)
    __shared__ float sa_s[32][4];         // 512 B   -> 61184 B total

    const int t    = threadIdx.x;
    const int row0 = blockIdx.x * 32;
    const int wid  = t >> 6;
    const int lane = t & 63;
    const int q    = lane >> 4;
    const int nl   = lane & 15;
    const half_t* fr_lo = frags + (size_t)FR_TOTAL * 512;

    // ---- GEMM1: latent1 = relu(cond @ w1 + b1), K=64; A direct from global ----
    {
        f32x4 c[2][2];
        #pragma unroll
        for (int rt = 0; rt < 2; ++rt)
            #pragma unroll
            for (int ic = 0; ic < 2; ++ic) c[rt][ic] = f32x4{0.f, 0.f, 0.f, 0.f};

        #pragma unroll
        for (int ks = 0; ks < 2; ++ks) {
            half8 ah[2], al[2];
            #pragma unroll
            for (int rt = 0; rt < 2; ++rt) {
                const float* src = cond + (size_t)(row0 + rt * 16 + nl) * 64 + ks * 32 + q * 8;
                float4 v0 = *reinterpret_cast<const float4*>(src);
                float4 v1 = *reinterpret_cast<const float4*>(src + 4);
                float vv[8] = {v0.x, v0.y, v0.z, v0.w, v1.x, v1.y, v1.z, v1.w};
                #pragma unroll
                for (int j = 0; j < 8; ++j) { half_t h, l; split16(vv[j], h, l); ah[rt][j] = h; al[rt][j] = l; }
            }
            #pragma unroll
            for (int ic = 0; ic < 2; ++ic) {
                int fidx = FR_G1 + ks * 16 + (wid * 2 + ic);
                half8 bh = *reinterpret_cast<const half8*>(frags + (size_t)fidx * 512 + lane * 8);
                half8 bl = *reinterpret_cast<const half8*>(fr_lo + (size_t)fidx * 512 + lane * 8);
                #pragma unroll
                for (int rt = 0; rt < 2; ++rt) {
                    c[rt][ic] = __builtin_amdgcn_mfma_f32_16x16x32_f16(ah[rt], bh, c[rt][ic], 0, 0, 0);
                    c[rt][ic] = __builtin_amdgcn_mfma_f32_16x16x32_f16(al[rt], bh, c[rt][ic], 0, 0, 0);
                    c[rt][ic] = __builtin_amdgcn_mfma_f32_16x16x32_f16(ah[rt], bl, c[rt][ic], 0, 0, 0);
                }
            }
        }
        // epilogue: relu+bias -> lat16 hi/lo. C/D: col=nl, row=q*4+reg
        #pragma unroll
        for (int ic = 0; ic < 2; ++ic) {
            int col = (wid * 2 + ic) * 16 + nl;
            float bv = b1[col];
            #pragma unroll
            for (int rt = 0; rt < 2; ++rt)
                #pragma unroll
                for (int reg = 0; reg < 4; ++reg) {
                    float y = fmaxf(c[rt][ic][reg] + bv, 0.f);
                    half_t h, l; split16(y, h, l);
                    int off = (rt * 16 + q * 4 + reg) * LT + col;
                    lat16h[off] = h; lat16l[off] = l;
                }
        }
    }
    __syncthreads();                                   // bar1: latent1 visible

    // ---- GEMM2: latent2 = relu(latent1 @ w2 + b2), K=256, in place ----
    {
        f32x4 c[2][2];
        #pragma unroll
        for (int rt = 0; rt < 2; ++rt)
            #pragma unroll
            for (int ic = 0; ic < 2; ++ic) c[rt][ic] = f32x4{0.f, 0.f, 0.f, 0.f};

        #pragma unroll
        for (int ks = 0; ks < 8; ++ks) {
            half8 ah[2], al[2];
            #pragma unroll
            for (int rt = 0; rt < 2; ++rt) {
                int off = (rt * 16 + nl) * LT + ks * 32 + q * 8;
                ah[rt] = *reinterpret_cast<const half8*>(lat16h + off);
                al[rt] = *reinterpret_cast<const half8*>(lat16l + off);
            }
            #pragma unroll
            for (int ic = 0; ic < 2; ++ic) {
                int fidx = FR_G2 + ks * 16 + (wid * 2 + ic);
                half8 bh = *reinterpret_cast<const half8*>(frags + (size_t)fidx * 512 + lane * 8);
                half8 bl = *reinterpret_cast<const half8*>(fr_lo + (size_t)fidx * 512 + lane * 8);
                #pragma unroll
                for (int rt = 0; rt < 2; ++rt) {
                    c[rt][ic] = __builtin_amdgcn_mfma_f32_16x16x32_f16(ah[rt], bh, c[rt][ic], 0, 0, 0);
                    c[rt][ic] = __builtin_amdgcn_mfma_f32_16x16x32_f16(al[rt], bh, c[rt][ic], 0, 0, 0);
                    c[rt][ic] = __builtin_amdgcn_mfma_f32_16x16x32_f16(ah[rt], bl, c[rt][ic], 0, 0, 0);
                }
            }
        }
        __syncthreads();                               // bar2: ALL latent1 reads done
        #pragma unroll
        for (int ic = 0; ic < 2; ++ic) {
            int col = (wid * 2 + ic) * 16 + nl;
            float bv = b2[col];
            #pragma unroll
            for (int rt = 0; rt < 2; ++rt)
                #pragma unroll
                for (int reg = 0; reg < 4; ++reg) {
                    float y = fmaxf(c[rt][ic][reg] + bv, 0.f);
                    half_t h, l; split16(y, h, l);
                    int off = (rt * 16 + q * 4 + reg) * LT + col;
                    lat16h[off] = h; lat16l[off] = l;
                }
        }
    }
    __syncthreads();                                   // bar3: latent2 visible

    float x = 0.f;

    // ---- spline chain, layer 3 -> 0, double-buffered pbuf (layer L -> buf L&1).
    // ONE barrier per layer: waves 1-7 K-loop(L) + write pbuf[L&1] -> barB(L) ->
    // wave-0 lanes run rqs(L) from pbuf[L&1] while waves 1-7 start K-loop(L-1).
    // Next write to buf L&1 is layer L-2, which happens after barB(L-1), and wave 0
    // reaches barB(L-1) only after rqs(L) completes -> no barA needed.
    for (int layer = 3; layer >= 0; --layer) {
        const int pb = layer & 1;
        f32x4 cpA[2], cpB[2];
        cpA[0] = f32x4{0.f, 0.f, 0.f, 0.f};
        cpA[1] = f32x4{0.f, 0.f, 0.f, 0.f};
        cpB[0] = f32x4{0.f, 0.f, 0.f, 0.f};
        cpB[1] = f32x4{0.f, 0.f, 0.f, 0.f};

        if (wid >= 1) {
            const int ct = wid - 1;
            #pragma unroll
            for (int ks = 0; ks < 8; ++ks) {
                half8 ah[2], al[2];
                #pragma unroll
                for (int rt = 0; rt < 2; ++rt) {
                    int off = (rt * 16 + nl) * LT + ks * 32 + q * 8;
                    ah[rt] = *reinterpret_cast<const half8*>(lat16h + off);
                    al[rt] = *reinterpret_cast<const half8*>(lat16l + off);
                }
                int fidx = FR_SP + layer * 56 + ks * 7 + ct;
                half8 bh = *reinterpret_cast<const half8*>(frags + (size_t)fidx * 512 + lane * 8);
                #pragma unroll
                for (int rt = 0; rt < 2; ++rt) {
                    cpA[rt] = __builtin_amdgcn_mfma_f32_16x16x32_f16(ah[rt], bh, cpA[rt], 0, 0, 0);
                    cpB[rt] = __builtin_amdgcn_mfma_f32_16x16x32_f16(al[rt], bh, cpB[rt], 0, 0, 0);
                }
            }
            cpA[0] += cpB[0];
            cpA[1] += cpB[1];
            // write params immediately (buffer pb is free: last touched at layer+2,
            // and its last readers finished before barB(layer+1))
            int n0 = (wid - 1) * 16 + nl;
            if (n0 < 97) {
                float sbv = sb[layer * 97 + n0];
                #pragma unroll
                for (int rt = 0; rt < 2; ++rt)
                    #pragma unroll
                    for (int reg = 0; reg < 4; ++reg)
                        pbuf[pb][rt * 16 + q * 4 + reg][n0] = cpA[rt][reg] + sbv;
            }
        } else if (layer == 3) {
            // aff on wave 0 (full 3-term; overlaps waves 1-7's layer-3 K-loop)
            #pragma unroll
            for (int ks = 0; ks < 8; ++ks) {
                half8 bh = *reinterpret_cast<const half8*>(frags + (size_t)(FR_AFF + ks) * 512 + lane * 8);
                half8 bl = *reinterpret_cast<const half8*>(fr_lo + (size_t)(FR_AFF + ks) * 512 + lane * 8);
                #pragma unroll
                for (int rt = 0; rt < 2; ++rt) {
                    int off = (rt * 16 + nl) * LT + ks * 32 + q * 8;
                    half8 ah = *reinterpret_cast<const half8*>(lat16h + off);
                    half8 al = *reinterpret_cast<const half8*>(lat16l + off);
                    cpA[rt] = __builtin_amdgcn_mfma_f32_16x16x32_f16(ah, bh, cpA[rt], 0, 0, 0);
                    cpB[rt] = __builtin_amdgcn_mfma_f32_16x16x32_f16(al, bh, cpB[rt], 0, 0, 0);
                    cpA[rt] = __builtin_amdgcn_mfma_f32_16x16x32_f16(ah, bl, cpA[rt], 0, 0, 0);
                }
            }
            cpA[0] += cpB[0];
            cpA[1] += cpB[1];
            if (nl < 4) {
                float abv = ab[nl];
                #pragma unroll
                for (int rt = 0; rt < 2; ++rt)
                    #pragma unroll
                    for (int reg = 0; reg < 4; ++reg)
                        sa_s[rt * 16 + q * 4 + reg][nl] = cpA[rt][reg] + abv;
            }
        }

        __syncthreads();   // barB(layer): params in pbuf[pb] + (L==3) sa visible
        if (t < 64) {
            int rrow = t >> 1;
            if (layer == 3) x = t_in[row0 + rrow] * __expf(sa_s[rrow][1]) + sa_s[rrow][0];
            x = rqs_coop2(x, &pbuf[pb][rrow][0], t);
            if (layer == 0 && (t & 1) == 0) {
                float xf = x * __expf(sa_s[rrow][3]) + sa_s[rrow][2];
                out[row0 + rrow] = 0.5f * (1.0f + erff(xf * 0.70710678118f));
            }
        }
    }
}

extern "C" void kernel_launch(void* const* d_in, const int* in_sizes, int n_in,
                              void* d_out, int out_size, void* d_ws, size_t ws_size,
                              hipStream_t stream) {
    const float* cond = (const float*)d_in[0];
    const float* t_in = (const float*)d_in[1];
    const float* w1   = (const float*)d_in[2];
    const float* b1   = (const float*)d_in[3];
    const float* w2   = (const float*)d_in[4];
    const float* b2   = (const float*)d_in[5];
    const float* sw   = (const float*)d_in[6];
    const float* sb   = (const float*)d_in[7];
    const float* aw   = (const float*)d_in[8];
    const float* ab   = (const float*)d_in[9];
    float* out = (float*)d_out;

    half_t* frags = (half_t*)d_ws;        // 784 KB of workspace (hi + lo blobs)

    prep_kernel<<<dim3(FR_TOTAL), dim3(64), 0, stream>>>(w1, w2, sw, aw, frags);

    const int B = out_size;               // 262144
    const int nblocks = B / 32;           // 8192
    condflow_kernel<<<dim3(nblocks), dim3(512), 0, stream>>>(
        cond, t_in, b1, b2, sb, ab, frags, out);
}

// Round 22
// 385.636 us; speedup vs baseline: 1.0228x; 1.0228x over previous
//
#include <hip/hip_runtime.h>
#include <math.h>

#define NB 32

typedef _Float16 half_t;
typedef _Float16 half8 __attribute__((ext_vector_type(8)));
typedef float f32x4 __attribute__((ext_vector_type(4)));

// fragment blob indices (each fragment = 512 half = 1 KB, lane-major: lane*8 halfs)
// B-frag: lane l holds B[k = ks*32 + (l>>4)*8 + j][n = ct*16 + (l&15)], j=0..7
// hi blob at frag f, lo blob at frag FR_TOTAL + f.
#define FR_G1  0      // ks(2)*16 + ct(16)                  -> 32 frags
#define FR_G2  32     // 32 + ks(8)*16 + ct(16)             -> 128
#define FR_SP  160    // 160 + layer*56 + ks(8)*7 + ct(7)   -> 224 (cols >=97 zero)
#define FR_AFF 384    // 384 + ks(8)                        -> 8 (cols >=4 zero)
#define FR_TOTAL 392  // hi+lo = 784 KB in d_ws

__device__ __forceinline__ void split16(float x, half_t& h, half_t& l) {
    h = (half_t)x;
    l = (half_t)(x - (float)h);
}

__global__ __launch_bounds__(64) void prep_kernel(
    const float* __restrict__ w1, const float* __restrict__ w2,
    const float* __restrict__ sw, const float* __restrict__ aw,
    half_t* __restrict__ frags)
{
    const int f = blockIdx.x;
    const int l = threadIdx.x;
    const int kl = (l >> 4) * 8;
    const int nl = l & 15;
    half8 vh, vl;
    #pragma unroll
    for (int j = 0; j < 8; ++j) {
        float w = 0.f;
        if (f < FR_G2) {
            int ks = f >> 4, ct = f & 15;
            w = w1[(ks * 32 + kl + j) * 256 + ct * 16 + nl];
        } else if (f < FR_SP) {
            int g = f - FR_G2;
            int ks = g >> 4, ct = g & 15;
            w = w2[(ks * 32 + kl + j) * 256 + ct * 16 + nl];
        } else if (f < FR_AFF) {
            int g = f - FR_SP;
            int layer = g / 56, r = g - layer * 56;
            int ks = r / 7, ct = r - ks * 7;
            int n = ct * 16 + nl;
            if (n < 97) w = sw[(size_t)layer * 24832 + (size_t)(ks * 32 + kl + j) * 97 + n];
        } else {
            int ks = f - FR_AFF;
            if (nl < 4) w = aw[(ks * 32 + kl + j) * 4 + nl];
        }
        half_t h, lo;
        split16(w, h, lo);
        vh[j] = h; vl[j] = lo;
    }
    *reinterpret_cast<half8*>(frags + (size_t)f * 512 + l * 8) = vh;
    *reinterpret_cast<half8*>(frags + (size_t)(FR_TOTAL + f) * 512 + l * 8) = vl;
}

__device__ __forceinline__ float softplus_f(float v) {
    return v > 0.f ? v + log1pf(__expf(-v)) : log1pf(__expf(v));
}

// Cooperative RQS on a LANE PAIR: lane (t&1)==l2 owns bins [l2*16, l2*16+16).
// p -> row's 97 params in LDS (read-only). Returns y (both lanes of the pair).
__device__ __forceinline__ float rqs_coop2(float x, const float* __restrict__ p, int lane) {
    const float RMIN = -3.0f;
    const float total = 6.0f - 32.0f * 1e-5f;
    const float OFF = 0.54130903f;                // log(exp(1-1e-5)-1)
    const int l2 = lane & 1;
    const int b0 = l2 * 16;

    // pass 1: pair max
    float mw = -INFINITY, mh = -INFINITY;
    #pragma unroll
    for (int i = 0; i < 16; ++i) {
        mw = fmaxf(mw, p[b0 + i]);
        mh = fmaxf(mh, p[NB + b0 + i]);
    }
    mw = fmaxf(mw, __shfl_xor(mw, 1));
    mh = fmaxf(mh, __shfl_xor(mh, 1));

    // pass 2: pair softmax denominators
    float swd = 0.f, shd = 0.f;
    #pragma unroll
    for (int i = 0; i < 16; ++i) {
        swd += __expf(p[b0 + i] - mw);
        shd += __expf(p[NB + b0 + i] - mh);
    }
    float swdo = __shfl_xor(swd, 1);
    float shdo = __shfl_xor(shd, 1);
    float sw_scale = total / (swd + swdo);
    float sh_scale = total / (shd + shdo);
    float prew = l2 ? (swdo * sw_scale + 16.f * 1e-5f) : 0.f;
    float preh = l2 ? (shdo * sh_scale + 16.f * 1e-5f) : 0.f;

    // pass 3: recompute exps, running cumsum, predicated capture of containing bin
    float cumw = 0.f, cumh = 0.f;
    float cw_c = 0.f, ch_c = 0.f, wk_c = 1.f, hk_c = 1.f;
    int idx_c = 0, cap = 0;
    #pragma unroll
    for (int i = 0; i < 16; ++i) {
        float wi = __expf(p[b0 + i] - mw) * sw_scale + 1e-5f;
        float hi = __expf(p[NB + b0 + i] - mh) * sh_scale + 1e-5f;
        float lw = prew + cumw;
        if (x >= RMIN + lw) {
            cw_c = lw; ch_c = preh + cumh; wk_c = wi; hk_c = hi;
            idx_c = b0 + i; cap = 1;
        }
        cumw += wi; cumh += hi;
    }

    // pair combine: lane1's capture wins when present
    const int hi_l = lane | 1, lo_l = lane & ~1;
    int   cap1 = __shfl(cap,  hi_l);
    float cw1 = __shfl(cw_c, hi_l), cw0 = __shfl(cw_c, lo_l);
    float ch1 = __shfl(ch_c, hi_l), ch0 = __shfl(ch_c, lo_l);
    float wk1 = __shfl(wk_c, hi_l), wk0 = __shfl(wk_c, lo_l);
    float hk1 = __shfl(hk_c, hi_l), hk0 = __shfl(hk_c, lo_l);
    int   ix1 = __shfl(idx_c, hi_l), ix0 = __shfl(idx_c, lo_l);
    float cw = cap1 ? cw1 : cw0;
    float ch = cap1 ? ch1 : ch0;
    float wk = cap1 ? wk1 : wk0;
    float hk = cap1 ? hk1 : hk0;
    int   idx = cap1 ? ix1 : ix0;

    float dk  = softplus_f(p[2 * NB + idx] + OFF) + 1e-5f;
    float dk1 = softplus_f(p[2 * NB + idx + 1] + OFF) + 1e-5f;

    float xk = RMIN + cw, yk = RMIN + ch;
    float z = (x - xk) / wk;
    z = fminf(fmaxf(z, 0.f), 1.f);
    float s = hk / wk;
    float z1 = z * (1.f - z);
    float num = hk * (s * z * z + dk * z1);
    float den = s + (dk1 + dk - 2.f * s) * z1;
    float y = yk + num / den;
    return (x < -3.0f || x > 3.0f) ? x : y;
}

#define LT 264    // lat16 row stride in halfs (528B)
#define PST 105   // pbuf row stride in floats (odd -> bank-spread reads)

// 32 rows/block, 512 threads (8 waves), LDS ~47.7 KB.
__global__ __launch_bounds__(512, 4) void condflow_kernel(
    const float* __restrict__ cond, const float* __restrict__ t_in,
    const float* __restrict__ b1, const float* __restrict__ b2,
    const float* __restrict__ sb, const float* __restrict__ ab,
    const half_t* __restrict__ frags,
    float* __restrict__ out)
{
    __shared__ half_t lat16h[32 * LT];    // 16896 B
    __shared__ half_t lat16l[32 * LT];    // 16896 B
    __shared__ float pbuf[32][PST];       // 13440 B (one layer's spline params)
    __shared__ float sa_s[32][4];         // 512 B   -> 47744 B total

    const int t    = threadIdx.x;
    const int row0 = blockIdx.x * 32;
    const int wid  = t >> 6;
    const int lane = t & 63;
    const int q    = lane >> 4;
    const int nl   = lane & 15;
    const half_t* fr_lo = frags + (size_t)FR_TOTAL * 512;

    // ---- GEMM1: latent1 = relu(cond @ w1 + b1), K=64; A direct from global ----
    {
        f32x4 c[2][2];
        #pragma unroll
        for (int rt = 0; rt < 2; ++rt)
            #pragma unroll
            for (int ic = 0; ic < 2; ++ic) c[rt][ic] = f32x4{0.f, 0.f, 0.f, 0.f};

        #pragma unroll
        for (int ks = 0; ks < 2; ++ks) {
            half8 ah[2], al[2];
            #pragma unroll
            for (int rt = 0; rt < 2; ++rt) {
                const float* src = cond + (size_t)(row0 + rt * 16 + nl) * 64 + ks * 32 + q * 8;
                float4 v0 = *reinterpret_cast<const float4*>(src);
                float4 v1 = *reinterpret_cast<const float4*>(src + 4);
                float vv[8] = {v0.x, v0.y, v0.z, v0.w, v1.x, v1.y, v1.z, v1.w};
                #pragma unroll
                for (int j = 0; j < 8; ++j) { half_t h, l; split16(vv[j], h, l); ah[rt][j] = h; al[rt][j] = l; }
            }
            #pragma unroll
            for (int ic = 0; ic < 2; ++ic) {
                int fidx = FR_G1 + ks * 16 + (wid * 2 + ic);
                half8 bh = *reinterpret_cast<const half8*>(frags + (size_t)fidx * 512 + lane * 8);
                half8 bl = *reinterpret_cast<const half8*>(fr_lo + (size_t)fidx * 512 + lane * 8);
                #pragma unroll
                for (int rt = 0; rt < 2; ++rt) {
                    c[rt][ic] = __builtin_amdgcn_mfma_f32_16x16x32_f16(ah[rt], bh, c[rt][ic], 0, 0, 0);
                    c[rt][ic] = __builtin_amdgcn_mfma_f32_16x16x32_f16(al[rt], bh, c[rt][ic], 0, 0, 0);
                    c[rt][ic] = __builtin_amdgcn_mfma_f32_16x16x32_f16(ah[rt], bl, c[rt][ic], 0, 0, 0);
                }
            }
        }
        // epilogue: relu+bias -> lat16 hi/lo. C/D: col=nl, row=q*4+reg
        #pragma unroll
        for (int ic = 0; ic < 2; ++ic) {
            int col = (wid * 2 + ic) * 16 + nl;
            float bv = b1[col];
            #pragma unroll
            for (int rt = 0; rt < 2; ++rt)
                #pragma unroll
                for (int reg = 0; reg < 4; ++reg) {
                    float y = fmaxf(c[rt][ic][reg] + bv, 0.f);
                    half_t h, l; split16(y, h, l);
                    int off = (rt * 16 + q * 4 + reg) * LT + col;
                    lat16h[off] = h; lat16l[off] = l;
                }
        }
    }
    __syncthreads();                                   // bar1: latent1 visible

    // ---- GEMM2: latent2 = relu(latent1 @ w2 + b2), K=256, in place ----
    {
        f32x4 c[2][2];
        #pragma unroll
        for (int rt = 0; rt < 2; ++rt)
            #pragma unroll
            for (int ic = 0; ic < 2; ++ic) c[rt][ic] = f32x4{0.f, 0.f, 0.f, 0.f};

        #pragma unroll
        for (int ks = 0; ks < 8; ++ks) {
            half8 ah[2], al[2];
            #pragma unroll
            for (int rt = 0; rt < 2; ++rt) {
                int off = (rt * 16 + nl) * LT + ks * 32 + q * 8;
                ah[rt] = *reinterpret_cast<const half8*>(lat16h + off);
                al[rt] = *reinterpret_cast<const half8*>(lat16l + off);
            }
            #pragma unroll
            for (int ic = 0; ic < 2; ++ic) {
                int fidx = FR_G2 + ks * 16 + (wid * 2 + ic);
                half8 bh = *reinterpret_cast<const half8*>(frags + (size_t)fidx * 512 + lane * 8);
                half8 bl = *reinterpret_cast<const half8*>(fr_lo + (size_t)fidx * 512 + lane * 8);
                #pragma unroll
                for (int rt = 0; rt < 2; ++rt) {
                    c[rt][ic] = __builtin_amdgcn_mfma_f32_16x16x32_f16(ah[rt], bh, c[rt][ic], 0, 0, 0);
                    c[rt][ic] = __builtin_amdgcn_mfma_f32_16x16x32_f16(al[rt], bh, c[rt][ic], 0, 0, 0);
                    c[rt][ic] = __builtin_amdgcn_mfma_f32_16x16x32_f16(ah[rt], bl, c[rt][ic], 0, 0, 0);
                }
            }
        }
        __syncthreads();                               // bar2: ALL latent1 reads done
        #pragma unroll
        for (int ic = 0; ic < 2; ++ic) {
            int col = (wid * 2 + ic) * 16 + nl;
            float bv = b2[col];
            #pragma unroll
            for (int rt = 0; rt < 2; ++rt)
                #pragma unroll
                for (int reg = 0; reg < 4; ++reg) {
                    float y = fmaxf(c[rt][ic][reg] + bv, 0.f);
                    half_t h, l; split16(y, h, l);
                    int off = (rt * 16 + q * 4 + reg) * LT + col;
                    lat16h[off] = h; lat16l[off] = l;
                }
        }
    }
    __syncthreads();                                   // bar3: latent2 visible

    float x = 0.f;

    // ---- spline chain, layer 3 -> 0.
    // waves 1..7: K-loop for layer L (ct = wid-1), spline-B h-only, with SPLIT
    // accumulator chains: cpA += ah*bh, cpB += al*bh (4 independent MFMA chains).
    // wave 0: aff at L==3 (full 3-term), then 2-lane-coop rqs at body end
    // (overlaps waves 1-7's K-loop of layer L-1).
    for (int layer = 3; layer >= 0; --layer) {
        f32x4 cpA[2], cpB[2];
        cpA[0] = f32x4{0.f, 0.f, 0.f, 0.f};
        cpA[1] = f32x4{0.f, 0.f, 0.f, 0.f};
        cpB[0] = f32x4{0.f, 0.f, 0.f, 0.f};
        cpB[1] = f32x4{0.f, 0.f, 0.f, 0.f};

        if (wid >= 1) {
            const int ct = wid - 1;
            #pragma unroll
            for (int ks = 0; ks < 8; ++ks) {
                half8 ah[2], al[2];
                #pragma unroll
                for (int rt = 0; rt < 2; ++rt) {
                    int off = (rt * 16 + nl) * LT + ks * 32 + q * 8;
                    ah[rt] = *reinterpret_cast<const half8*>(lat16h + off);
                    al[rt] = *reinterpret_cast<const half8*>(lat16l + off);
                }
                int fidx = FR_SP + layer * 56 + ks * 7 + ct;
                half8 bh = *reinterpret_cast<const half8*>(frags + (size_t)fidx * 512 + lane * 8);
                #pragma unroll
                for (int rt = 0; rt < 2; ++rt) {
                    cpA[rt] = __builtin_amdgcn_mfma_f32_16x16x32_f16(ah[rt], bh, cpA[rt], 0, 0, 0);
                    cpB[rt] = __builtin_amdgcn_mfma_f32_16x16x32_f16(al[rt], bh, cpB[rt], 0, 0, 0);
                }
            }
            // merge the two partial-sum chains
            cpA[0] += cpB[0];
            cpA[1] += cpB[1];
        } else if (layer == 3) {
            // aff on wave 0 (full 3-term; only pass where it has no pending rqs)
            #pragma unroll
            for (int ks = 0; ks < 8; ++ks) {
                half8 bh = *reinterpret_cast<const half8*>(frags + (size_t)(FR_AFF + ks) * 512 + lane * 8);
                half8 bl = *reinterpret_cast<const half8*>(fr_lo + (size_t)(FR_AFF + ks) * 512 + lane * 8);
                #pragma unroll
                for (int rt = 0; rt < 2; ++rt) {
                    int off = (rt * 16 + nl) * LT + ks * 32 + q * 8;
                    half8 ah = *reinterpret_cast<const half8*>(lat16h + off);
                    half8 al = *reinterpret_cast<const half8*>(lat16l + off);
                    cpA[rt] = __builtin_amdgcn_mfma_f32_16x16x32_f16(ah, bh, cpA[rt], 0, 0, 0);
                    cpB[rt] = __builtin_amdgcn_mfma_f32_16x16x32_f16(al, bh, cpB[rt], 0, 0, 0);
                    cpA[rt] = __builtin_amdgcn_mfma_f32_16x16x32_f16(ah, bl, cpA[rt], 0, 0, 0);
                }
            }
            cpA[0] += cpB[0];
            cpA[1] += cpB[1];
            if (nl < 4) {
                float abv = ab[nl];
                #pragma unroll
                for (int rt = 0; rt < 2; ++rt)
                    #pragma unroll
                    for (int reg = 0; reg < 4; ++reg)
                        sa_s[rt * 16 + q * 4 + reg][nl] = cpA[rt][reg] + abv;
            }
        }

        __syncthreads();   // barA: wave0's rqs(layer+1) done with pbuf; (L==3) sa computed
        if (wid >= 1) {
            int n0 = (wid - 1) * 16 + nl;
            if (n0 < 97) {
                float sbv = sb[layer * 97 + n0];
                #pragma unroll
                for (int rt = 0; rt < 2; ++rt)
                    #pragma unroll
                    for (int reg = 0; reg < 4; ++reg)
                        pbuf[rt * 16 + q * 4 + reg][n0] = cpA[rt][reg] + sbv;
            }
        }
        __syncthreads();   // barB: params visible
        if (t < 64) {
            int rrow = t >> 1;
            if (layer == 3) x = t_in[row0 + rrow] * __expf(sa_s[rrow][1]) + sa_s[rrow][0];
            x = rqs_coop2(x, &pbuf[rrow][0], t);
            if (layer == 0 && (t & 1) == 0) {
                float xf = x * __expf(sa_s[rrow][3]) + sa_s[rrow][2];
                out[row0 + rrow] = 0.5f * (1.0f + erff(xf * 0.70710678118f));
            }
        }
    }
}

extern "C" void kernel_launch(void* const* d_in, const int* in_sizes, int n_in,
                              void* d_out, int out_size, void* d_ws, size_t ws_size,
                              hipStream_t stream) {
    const float* cond = (const float*)d_in[0];
    const float* t_in = (const float*)d_in[1];
    const float* w1   = (const float*)d_in[2];
    const float* b1   = (const float*)d_in[3];
    const float* w2   = (const float*)d_in[4];
    const float* b2   = (const float*)d_in[5];
    const float* sw   = (const float*)d_in[6];
    const float* sb   = (const float*)d_in[7];
    const float* aw   = (const float*)d_in[8];
    const float* ab   = (const float*)d_in[9];
    float* out = (float*)d_out;

    half_t* frags = (half_t*)d_ws;        // 784 KB of workspace (hi + lo blobs)

    prep_kernel<<<dim3(FR_TOTAL), dim3(64), 0, stream>>>(w1, w2, sw, aw, frags);

    const int B = out_size;               // 262144
    const int nblocks = B / 32;           // 8192
    condflow_kernel<<<dim3(nblocks), dim3(512), 0, stream>>>(
        cond, t_in, b1, b2, sb, ab, frags, out);
}